// Round 19
// baseline (75.104 us; speedup 1.0000x reference)
//
#include <hip/hip_runtime.h>

// Sinkhorn (eps=0.2, 50 iters), 64x64 images, b=64. Separable Gibbs kernel,
// 3-tap truncated (R13-validated; +-2 taps weigh e^-20 ~ 2e-9, absmax 0).
//
// R19: TWO-IMAGE INSTRUCTION-LEVEL INTERLEAVE. 32 blocks x 4 waves; wave w
// owns cols 16w..16w+15 of BOTH image 2b and image 2b+1, two independent
// iteration chains in one instruction stream. Every phase-locked stall that
// resisted R10/R14/R15/R18 (LDS round-trip, DPP/trans dep bubbles, barrier
// skew -- ~820 cyc/iter) gets filled by the other chain's VALU work; the
// scheduler interleaves freely because there is no dependence and no barrier
// between the two COMPUTEs. ONE barrier per iteration serves both images
// (publish A+B -> barrier -> read A+B halos).
// Per-element arithmetic bitwise identical to R16/R18 (guard +1e-8 semantic,
// kept exactly; raw v_rcp; DPP bound_ctrl 0-fill edges).

template<int CTRL>
__device__ __forceinline__ float dppf(float v) {
    return __builtin_bit_cast(float,
        __builtin_amdgcn_update_dpp(0, __builtin_bit_cast(int, v),
                                    CTRL, 0xF, 0xF, true));
}
#define SHR1(v) dppf<0x138>(v)   // out[r] = in[r-1], row 0 gets 0
#define SHL1(v) dppf<0x130>(v)   // out[r] = in[r+1], row 63 gets 0

// Phases A-D for one image (no barrier). V_: 20 cols in/out; U_: 18 out.
#define COMPUTE(V_, U_, xv_, yv_)                                              \
  {                                                                            \
    float am[20], ap[20], tv[20];                                              \
    _Pragma("unroll") for (int j = 0; j < 20; ++j) am[j] = SHR1(V_[j]);        \
    _Pragma("unroll") for (int j = 0; j < 20; ++j) ap[j] = SHL1(V_[j]);        \
    _Pragma("unroll") for (int j = 0; j < 20; ++j) am[j] = am[j] + ap[j];      \
    _Pragma("unroll") for (int j = 0; j < 20; ++j) tv[j] = fmaf(g1, am[j], V_[j]); \
    float pre[19];                                                             \
    _Pragma("unroll") for (int j = 1; j < 19; ++j)                             \
      pre[j] = fmaf(g1, tv[j-1] + tv[j+1], tv[j] + 1e-8f);                     \
    _Pragma("unroll") for (int j = 1; j < 19; ++j)                             \
      U_[j-1] = xv_[j-1] * __builtin_amdgcn_rcpf(pre[j]);                      \
    float bm[18], bp[18], tu[18];                                              \
    _Pragma("unroll") for (int j = 0; j < 18; ++j) bm[j] = SHR1(U_[j]);        \
    _Pragma("unroll") for (int j = 0; j < 18; ++j) bp[j] = SHL1(U_[j]);        \
    _Pragma("unroll") for (int j = 0; j < 18; ++j) bm[j] = bm[j] + bp[j];      \
    _Pragma("unroll") for (int j = 0; j < 18; ++j) tu[j] = fmaf(g1, bm[j], U_[j]); \
    _Pragma("unroll") for (int m = 1; m < 17; ++m) {                           \
      float pr_ = fmaf(g1, tu[m-1] + tu[m+1], tu[m] + 1e-8f);                  \
      V_[m+1] = yv_[m-1] * __builtin_amdgcn_rcpf(pr_);                         \
    }                                                                          \
  }

#define PUBLISH(V_, EBP_)                                                      \
  { float* pub_ = &(EBP_)[(w + 1) * 256 + r];                                  \
    pub_[0]   = V_[2];  pub_[64]  = V_[3];                                     \
    pub_[128] = V_[16]; pub_[192] = V_[17]; }

#define READHALO(V_, EBP_)                                                     \
  { const float* lh_ = &(EBP_)[w * 256 + r];                                   \
    const float* rh_ = &(EBP_)[(w + 2) * 256 + r];                             \
    V_[0]  = lh_[128]; V_[1]  = lh_[192];                                      \
    V_[18] = rh_[0];   V_[19] = rh_[64]; }

extern "C" __global__ void __launch_bounds__(256, 1)
sinkhorn_kernel(const float* __restrict__ x, const float* __restrict__ y,
                const float* __restrict__ cost, const float* __restrict__ kern,
                float* __restrict__ partials)
{
    // EB[parity][image][6 regions x 256]; regions 0 and 5 stay zero forever
    // (image col zero-padding). 2*2*1536*4 = 24.6 KB.
    __shared__ float EB[2][2][1536];
    __shared__ float wsumA[4], wsumB[4];

    const int t = threadIdx.x;
    const int r = t & 63;        // lane = row
    const int w = t >> 6;        // wave = col group (own cols 16w..16w+15)
    const int b = blockIdx.x;    // block handles images 2b and 2b+1

    for (int i = t; i < 6144; i += 256) (&EB[0][0][0])[i] = 0.0f;

    const float g1 = kern[(size_t)64  * 4096];        // e^-5
    const float q1 = cost[(size_t)64  * 4096] * g1;   // 1*e^-5

    // marginals for both images at this thread's tile
    float xvA[18], yvA[16], xvB[18], yvB[16];
    {
        const float* xrA = x + (size_t)(2*b)     * 4096 + 64 * r;
        const float* xrB = x + (size_t)(2*b + 1) * 4096 + 64 * r;
#pragma unroll
        for (int j = 0; j < 18; ++j) {
            int cc = 16 * w - 1 + j;
            cc = cc < 0 ? 0 : (cc > 63 ? 63 : cc);
            xvA[j] = xrA[cc];
            xvB[j] = xrB[cc];
        }
        if (w == 0) { xvA[0]  = 0.0f; xvB[0]  = 0.0f; }
        if (w == 3) { xvA[17] = 0.0f; xvB[17] = 0.0f; }
        const float* ybA = y + (size_t)(2*b)     * 4096 + 64 * r + 16 * w;
        const float* ybB = y + (size_t)(2*b + 1) * 4096 + 64 * r + 16 * w;
#pragma unroll
        for (int j = 0; j < 4; ++j) {
            float4 f = *(const float4*)(ybA + 4 * j);
            yvA[4*j] = f.x; yvA[4*j+1] = f.y; yvA[4*j+2] = f.z; yvA[4*j+3] = f.w;
            f = *(const float4*)(ybB + 4 * j);
            yvB[4*j] = f.x; yvB[4*j+1] = f.y; yvB[4*j+2] = f.z; yvB[4*j+3] = f.w;
        }
    }

    // state per image: V on 20 cols [16w-2,16w+17], U on 18 cols
    float VA[20], UA[18], VB[20], UB[18];
#pragma unroll
    for (int j = 0; j < 20; ++j) { VA[j] = 1.0f / 4096.0f; VB[j] = 1.0f / 4096.0f; }
    if (w == 0) { VA[0] = VA[1] = 0.0f;  VB[0] = VB[1] = 0.0f; }
    if (w == 3) { VA[18] = VA[19] = 0.0f; VB[18] = VB[19] = 0.0f; }
    __syncthreads();   // EB fully zeroed before any publish

#pragma unroll 1
    for (int it2 = 0; it2 < 25; ++it2) {
        COMPUTE(VA, UA, xvA, yvA)
        COMPUTE(VB, UB, xvB, yvB)
        PUBLISH(VA, EB[0][0])
        PUBLISH(VB, EB[0][1])
        __syncthreads();
        READHALO(VA, EB[0][0])
        READHALO(VB, EB[0][1])

        COMPUTE(VA, UA, xvA, yvA)
        COMPUTE(VB, UB, xvB, yvB)
        PUBLISH(VA, EB[1][0])
        PUBLISH(VB, EB[1][1])
        __syncthreads();
        READHALO(VA, EB[1][0])
        READHALO(VB, EB[1][1])
    }

    // ---- distance per image: sum_own U o ((G2*V)*G) + U o ((G*V)*G2)
    float accA = 0.0f, accB = 0.0f;
#define DIST(V_, U_, acc_)                                                     \
    {                                                                          \
        float nn[20], tq[20], tg[20];                                          \
        _Pragma("unroll") for (int j = 0; j < 20; ++j) nn[j] = SHR1(V_[j]) + SHL1(V_[j]); \
        _Pragma("unroll") for (int j = 0; j < 20; ++j) tq[j] = q1 * nn[j];     \
        _Pragma("unroll") for (int j = 0; j < 20; ++j) tg[j] = fmaf(g1, nn[j], V_[j]); \
        _Pragma("unroll") for (int k = 2; k < 18; ++k) {                       \
            float m1 = fmaf(g1, tq[k-1] + tq[k+1], tq[k]);                     \
            acc_ = fmaf(U_[k-1], m1, acc_);                                    \
        }                                                                      \
        _Pragma("unroll") for (int k = 2; k < 18; ++k) {                       \
            float m2 = q1 * (tg[k-1] + tg[k+1]);                               \
            acc_ = fmaf(U_[k-1], m2, acc_);                                    \
        }                                                                      \
    }
    DIST(VA, UA, accA)
    DIST(VB, UB, accB)

    // per-block reduction per image: wave shfl tree + fixed-order 4-way sum
#pragma unroll
    for (int off = 32; off > 0; off >>= 1) {
        accA += __shfl_down(accA, off, 64);
        accB += __shfl_down(accB, off, 64);
    }
    if (r == 0) { wsumA[w] = accA; wsumB[w] = accB; }
    __syncthreads();
    if (t == 0) {
        partials[2*b]     = (wsumA[0] + wsumA[1]) + (wsumA[2] + wsumA[3]);
        partials[2*b + 1] = (wsumB[0] + wsumB[1]) + (wsumB[2] + wsumB[3]);
    }
}

extern "C" __global__ void __launch_bounds__(64)
reduce_kernel(const float* __restrict__ partials, float* __restrict__ out)
{
    int t = threadIdx.x;
    float v = partials[t];
#pragma unroll
    for (int off = 32; off > 0; off >>= 1)
        v += __shfl_down(v, off, 64);
    if (t == 0) out[0] = v;
}

extern "C" void kernel_launch(void* const* d_in, const int* in_sizes, int n_in,
                              void* d_out, int out_size, void* d_ws, size_t ws_size,
                              hipStream_t stream)
{
    const float* x    = (const float*)d_in[0];
    const float* y    = (const float*)d_in[1];
    const float* cost = (const float*)d_in[2];
    const float* kern = (const float*)d_in[3];
    float* partials   = (float*)d_ws;   // 64 floats

    sinkhorn_kernel<<<32, 256, 0, stream>>>(x, y, cost, kern, partials);
    reduce_kernel<<<1, 64, 0, stream>>>(partials, (float*)d_out);
}

// Round 20
// 43.398 us; speedup vs baseline: 1.7306x; 1.7306x over previous
//
#include <hip/hip_runtime.h>

// Sinkhorn (eps=0.2, 50 iters), 64x64 images, b=64. Separable Gibbs kernel,
// 3-tap truncated (R13-validated: +-2 taps weigh e^-20 ~ 2e-9, absmax 0).
// Topology: 64 blocks x 4 waves x 16 own cols, lane = row; V held on 20 cols
// [16w-2,16w+17], U on 18 cols; ONE exchange (4 conflict-free b32 writes +
// 1 barrier + 4 reads, parity-double-buffered) per iteration.
//
// R20 = R16 verbatim (best measured: dur 43.3us, kernel 39.1us, absmax 0.0).
// R19's two-image interleave refuted the "fillable stall" theory (VGPR=112,
// kernel 72us): per-image VALU issue is ~1050 cyc/iter regardless; the
// remaining ~40% latency (barrier + LDS round-trip + DPP/trans bubbles on a
// serial 100-apply chain at 1 wave/SIMD) resisted R10/R11/R14/R15/R18/R19.
// Floor arithmetic: 50 x 1050 cyc = 21.9us pure-issue at the 64-image
// parallelism cap; kernel 39us = 1.8x that; +4.2us two-dispatch launch path.

template<int CTRL>
__device__ __forceinline__ float dppf(float v) {
    return __builtin_bit_cast(float,
        __builtin_amdgcn_update_dpp(0, __builtin_bit_cast(int, v),
                                    CTRL, 0xF, 0xF, true));
}
#define SHR1(v) dppf<0x138>(v)   // out[r] = in[r-1], row 0 gets 0
#define SHL1(v) dppf<0x130>(v)   // out[r] = in[r+1], row 63 gets 0

// One iteration; EBP = parity exchange buffer base.
#define BODY(EBP)                                                              \
  {                                                                            \
    /* Phase A: vertical G on V (20 cols); interior first, halo cols last */   \
    float am[20], ap[20], tv[20], tvc[19];                                     \
    _Pragma("unroll") for (int j = 2; j < 18; ++j) am[j] = SHR1(V[j]);         \
    _Pragma("unroll") for (int j = 2; j < 18; ++j) ap[j] = SHL1(V[j]);         \
    _Pragma("unroll") for (int j = 2; j < 18; ++j) am[j] = am[j] + ap[j];      \
    _Pragma("unroll") for (int j = 2; j < 18; ++j) tv[j] = fmaf(g1, am[j], V[j]); \
    am[0] = SHR1(V[0]); am[1] = SHR1(V[1]);                                    \
    am[18] = SHR1(V[18]); am[19] = SHR1(V[19]);                                \
    ap[0] = SHL1(V[0]); ap[1] = SHL1(V[1]);                                    \
    ap[18] = SHL1(V[18]); ap[19] = SHL1(V[19]);                                \
    am[0] += ap[0]; am[1] += ap[1]; am[18] += ap[18]; am[19] += ap[19];        \
    tv[0]  = fmaf(g1, am[0],  V[0]);  tv[1]  = fmaf(g1, am[1],  V[1]);         \
    tv[18] = fmaf(g1, am[18], V[18]); tv[19] = fmaf(g1, am[19], V[19]);        \
    _Pragma("unroll") for (int j = 1; j < 19; ++j) tvc[j] = tv[j] + 1e-8f;     \
    /* Phase B: horizontal G + reciprocal -> U (18 cols) */                    \
    float pre[19], rq[19];                                                     \
    _Pragma("unroll") for (int j = 1; j < 19; ++j)                             \
      pre[j] = fmaf(g1, tv[j-1] + tv[j+1], tvc[j]);                            \
    _Pragma("unroll") for (int j = 1; j < 19; ++j)                             \
      rq[j] = __builtin_amdgcn_rcpf(pre[j]);                                   \
    _Pragma("unroll") for (int j = 1; j < 19; ++j) U[j-1] = xv[j-1] * rq[j];   \
    /* Phase C: vertical G on U (18 cols) */                                   \
    float bm[18], bp[18], tu[18], tuc[17];                                     \
    _Pragma("unroll") for (int j = 0; j < 18; ++j) bm[j] = SHR1(U[j]);         \
    _Pragma("unroll") for (int j = 0; j < 18; ++j) bp[j] = SHL1(U[j]);         \
    _Pragma("unroll") for (int j = 0; j < 18; ++j) bm[j] = bm[j] + bp[j];      \
    _Pragma("unroll") for (int j = 0; j < 18; ++j) tu[j] = fmaf(g1, bm[j], U[j]); \
    _Pragma("unroll") for (int j = 1; j < 17; ++j) tuc[j] = tu[j] + 1e-8f;     \
    /* Phase D: horizontal G + reciprocal -> V own 16 cols */                  \
    float pr2[17], rq2[17];                                                    \
    _Pragma("unroll") for (int m = 1; m < 17; ++m)                             \
      pr2[m] = fmaf(g1, tu[m-1] + tu[m+1], tuc[m]);                            \
    _Pragma("unroll") for (int m = 1; m < 17; ++m)                             \
      rq2[m] = __builtin_amdgcn_rcpf(pr2[m]);                                  \
    _Pragma("unroll") for (int m = 1; m < 17; ++m) V[m+1] = yv[m-1] * rq2[m];  \
    /* exchange: publish own edges, barrier, read halos */                     \
    float* pub_ = &(EBP)[(w + 1) * 256 + r];                                   \
    pub_[0]   = V[2];  pub_[64]  = V[3];                                       \
    pub_[128] = V[16]; pub_[192] = V[17];                                      \
    __syncthreads();                                                           \
    const float* lh_ = &(EBP)[w * 256 + r];                                    \
    const float* rh_ = &(EBP)[(w + 2) * 256 + r];                              \
    V[0]  = lh_[128]; V[1]  = lh_[192];                                        \
    V[18] = rh_[0];   V[19] = rh_[64];                                         \
  }

extern "C" __global__ void __launch_bounds__(256)
sinkhorn_kernel(const float* __restrict__ x, const float* __restrict__ y,
                const float* __restrict__ cost, const float* __restrict__ kern,
                float* __restrict__ partials)
{
    // per parity: 6 regions x 256 floats (4 edge slots x 64 lanes);
    // regions 0 and 5 are permanent zero guards (image col zero-padding).
    __shared__ float EB[2][1536];
    __shared__ float wsum[4];

    const int t = threadIdx.x;
    const int r = t & 63;        // lane = row
    const int w = t >> 6;        // wave = col group (own cols 16w..16w+15)
    const int b = blockIdx.x;

    for (int i = t; i < 3072; i += 256) ((float*)EB)[i] = 0.0f;

    const float g1 = kern[(size_t)64  * 4096];        // e^-5
    const float q1 = cost[(size_t)64  * 4096] * g1;   // 1*e^-5

    // marginals: xv on 18 cols [16w-1,16w+16] (clamped loads; edge cols
    // premasked to 0 -> U edge masking for free), yv on own 16 cols.
    float xv[18], yv[16];
    {
        const float* xr = x + (size_t)b * 4096 + 64 * r;
#pragma unroll
        for (int j = 0; j < 18; ++j) {
            int cc = 16 * w - 1 + j;
            cc = cc < 0 ? 0 : (cc > 63 ? 63 : cc);
            xv[j] = xr[cc];
        }
        if (w == 0) xv[0]  = 0.0f;
        if (w == 3) xv[17] = 0.0f;
        const float* yb = y + (size_t)b * 4096 + 64 * r + 16 * w;
#pragma unroll
        for (int j = 0; j < 4; ++j) {
            float4 f = *(const float4*)(yb + 4 * j);
            yv[4*j] = f.x; yv[4*j+1] = f.y; yv[4*j+2] = f.z; yv[4*j+3] = f.w;
        }
    }

    // V on 20 cols [16w-2, 16w+17]; U on 18 cols [16w-1, 16w+16]
    float V[20], U[18];
#pragma unroll
    for (int j = 0; j < 20; ++j) V[j] = 1.0f / 4096.0f;
    if (w == 0) { V[0]  = 0.0f; V[1]  = 0.0f; }
    if (w == 3) { V[18] = 0.0f; V[19] = 0.0f; }
    __syncthreads();   // EB fully zeroed before any publish

#pragma unroll 1
    for (int it2 = 0; it2 < 25; ++it2) {
        BODY(EB[0])
        BODY(EB[1])
    }

    // ---- distance: sum_own U o ((G2*V)*G) + U o ((G*V)*G2); registers only
    float acc = 0.0f;
    {
        float nn[20], tq[20], tg[20];
#pragma unroll
        for (int j = 0; j < 20; ++j) nn[j] = SHR1(V[j]) + SHL1(V[j]);
#pragma unroll
        for (int j = 0; j < 20; ++j) tq[j] = q1 * nn[j];
#pragma unroll
        for (int j = 0; j < 20; ++j) tg[j] = fmaf(g1, nn[j], V[j]);
#pragma unroll
        for (int k = 2; k < 18; ++k) {
            float m1 = fmaf(g1, tq[k-1] + tq[k+1], tq[k]);   // (G2*V)*G
            acc = fmaf(U[k-1], m1, acc);
        }
#pragma unroll
        for (int k = 2; k < 18; ++k) {
            float m2 = q1 * (tg[k-1] + tg[k+1]);             // (G*V)*G2
            acc = fmaf(U[k-1], m2, acc);
        }
    }

    // per-block reduction: wave shfl tree, then fixed-order 4-way sum
#pragma unroll
    for (int off = 32; off > 0; off >>= 1)
        acc += __shfl_down(acc, off, 64);
    if (r == 0) wsum[w] = acc;
    __syncthreads();
    if (t == 0)
        partials[b] = (wsum[0] + wsum[1]) + (wsum[2] + wsum[3]);
}

extern "C" __global__ void __launch_bounds__(64)
reduce_kernel(const float* __restrict__ partials, float* __restrict__ out)
{
    int t = threadIdx.x;
    float v = partials[t];
#pragma unroll
    for (int off = 32; off > 0; off >>= 1)
        v += __shfl_down(v, off, 64);
    if (t == 0) out[0] = v;
}

extern "C" void kernel_launch(void* const* d_in, const int* in_sizes, int n_in,
                              void* d_out, int out_size, void* d_ws, size_t ws_size,
                              hipStream_t stream)
{
    const float* x    = (const float*)d_in[0];
    const float* y    = (const float*)d_in[1];
    const float* cost = (const float*)d_in[2];
    const float* kern = (const float*)d_in[3];
    float* partials   = (float*)d_ws;   // 64 floats

    sinkhorn_kernel<<<64, 256, 0, stream>>>(x, y, cost, kern, partials);
    reduce_kernel<<<1, 64, 0, stream>>>(partials, (float*)d_out);
}